// Round 19
// baseline (182.146 us; speedup 1.0000x reference)
//
#include <hip/hip_runtime.h>

#define WF 512
#define HF 256
#define CF 64
#define ND 65
#define AP 40            // f16 ch-stride of SA/SB tiles (80 B, 16B-aligned reads)
#define GS 65            // f16 d-stride of G ring rows
#define GROW 130         // rows per G slot: xl = -1 .. 128

static constexpr size_t CH = (size_t)HF * WF;
static constexpr size_t WH = (size_t)HF * WF;
static constexpr float  INV = 1.0f / 576.0f;

typedef _Float16 f16;
typedef _Float16 f16x8 __attribute__((ext_vector_type(8)));
typedef float    f32x4 __attribute__((ext_vector_type(4)));
typedef float    f32x2 __attribute__((ext_vector_type(2)));

// ---------------------------------------------------------------------------
// FUSED kernel (R19 = R18 + f32x2 nt-store fix): correlation = banded Gram
// (MFMA, single-f16, validated R16/R17) + 3x3 box-sum, NO ws intermediate.
// Block = (b, 128-col strip s, 8-row y-tile g); 512 thr = 8 waves.
// Loop r=0..9 over rows yy=y0-1+r (2 halo rows recomputed):
//   - stage x0 cols [X0-4,X0+132) + x1 cols [X0-36,X0+180) per 32-ch half
//     as f16 col-major LDS (f32x4 contiguous bursts, OOB zeroed);
//   - 8 MFMA x-tiles (wave w = tile w), 5 band offsets -> G[x, x+d-32];
//   - scatter into G-ring slot r%3 ([130 x][65 d] f16); edge cols x=X0-1,
//     X0+128 via 65-thread LDS dot products (zero-pad-correct via staging);
//   - when 3 rows live: out[d][ye][x] = INV * sum 3x3 ring values,
//     coalesced nontemporal f32x2 stores.
// Band mapping d = 16p+n-m, C/D layout, frag layout: validated R5-R17.
// ---------------------------------------------------------------------------
__global__ __launch_bounds__(512, 2)
void corr_fused(const float* __restrict__ x0, const float* __restrict__ x1,
                float* __restrict__ out) {
    // XCD swizzle: adjacent y-tiles and both strips of one b on one XCD.
    const int f = blockIdx.x;             // [0, 512)
    const int unit = (f & 7) * 64 + (f >> 3);
    const int b = unit >> 7;              // [0,4)
    const int rem = unit & 127;
    const int s = rem >> 5;               // [0,4)
    const int g = rem & 31;               // [0,32)
    const int X0 = s << 7;
    const int y0 = g << 3;

    const int t = threadIdx.x;
    const int l = t & 63;
    const int w = t >> 6;                 // wave = x-tile index [0,8)
    const int n = l & 15;
    const int kq = l >> 4;

    __shared__ f16 SA[136 * AP];          // x0 cols X0-4 .. X0+131 (per half)
    __shared__ f16 SB[216 * AP];          // x1 cols X0-36 .. X0+179 (per half)
    __shared__ f16 GR[3 * GROW * GS];     // ring of 3 G row tiles

    const float* x0bb = x0 + (size_t)b * CF * CH;
    const float* x1bb = x1 + (size_t)b * CF * CH;
    float* outb = out + (size_t)b * ND * WH;

#pragma unroll 1
    for (int r = 0; r < 10; ++r) {
        const int yy = y0 - 1 + r;
        f16* Gs = GR + (r % 3) * (GROW * GS);

        if ((unsigned)yy < (unsigned)HF) {
            const float* x0r = x0bb + (size_t)yy * WF;
            const float* x1r = x1bb + (size_t)yy * WF;

            float la = 0.f, ra = 0.f;     // edge dot accumulators
            f32x4 acc[5];
#pragma unroll
            for (int p = 0; p < 5; ++p) acc[p] = (f32x4)0.0f;

#pragma unroll
            for (int h = 0; h < 2; ++h) {
                // ---- stage half h (32 channels) ----
                f32x4 av[3], bv[4];
#pragma unroll
                for (int k = 0; k < 3; ++k) {
                    const int u = t + 512 * k;
                    av[k] = (f32x4)0.0f;
                    if (u < 1088) {
                        const int c = u / 34, cg = u - 34 * c;
                        const int col = X0 - 4 + 4 * cg;
                        if (col >= 0 && col <= 508)
                            av[k] = *(const f32x4*)(x0r + (size_t)(32 * h + c) * CH + col);
                    }
                }
#pragma unroll
                for (int k = 0; k < 4; ++k) {
                    const int u = t + 512 * k;
                    bv[k] = (f32x4)0.0f;
                    if (u < 1728) {
                        const int c = u / 54, cg = u - 54 * c;
                        const int col = X0 - 36 + 4 * cg;
                        if (col >= 0 && col <= 508)
                            bv[k] = *(const f32x4*)(x1r + (size_t)(32 * h + c) * CH + col);
                    }
                }
#pragma unroll
                for (int k = 0; k < 3; ++k) {
                    const int u = t + 512 * k;
                    if (u < 1088) {
                        const int c = u / 34, cg = u - 34 * c;
#pragma unroll
                        for (int jj = 0; jj < 4; ++jj)
                            SA[(4 * cg + jj) * AP + c] = (f16)av[k][jj];
                    }
                }
#pragma unroll
                for (int k = 0; k < 4; ++k) {
                    const int u = t + 512 * k;
                    if (u < 1728) {
                        const int c = u / 54, cg = u - 54 * c;
#pragma unroll
                        for (int jj = 0; jj < 4; ++jj)
                            SB[(4 * cg + jj) * AP + c] = (f16)bv[k][jj];
                    }
                }
                __syncthreads();          // half staged

                // ---- MFMA: wave w = x-tile w; 5 band offsets ----
                const f16x8 a = *(const f16x8*)&SA[(4 + 16 * w + n) * AP + kq * 8];
#pragma unroll
                for (int p = 0; p < 5; ++p) {
                    const f16x8 bf = *(const f16x8*)&SB[(16 * (w + p) + n + 4) * AP + kq * 8];
                    acc[p] = __builtin_amdgcn_mfma_f32_16x16x32_f16(a, bf, acc[p], 0, 0, 0);
                }
                // ---- edge dots (x = X0-1 and X0+128), LDS-only ----
                if (t < 65) {
#pragma unroll
                    for (int c = 0; c < 32; ++c)
                        la += (float)SA[3 * AP + c] * (float)SB[(t + 3) * AP + c];
                }
                if (t >= 256 && t < 321) {
                    const int d = t - 256;
#pragma unroll
                    for (int c = 0; c < 32; ++c)
                        ra += (float)SA[132 * AP + c] * (float)SB[(132 + d) * AP + c];
                }
                __syncthreads();          // all SA/SB readers done
            }

            // ---- scatter band into G ring slot ----
#pragma unroll
            for (int p = 0; p < 5; ++p) {
#pragma unroll
                for (int q = 0; q < 4; ++q) {
                    const int m = kq * 4 + q;
                    const int d = 16 * p + n - m;
                    if ((unsigned)d < (unsigned)ND)
                        Gs[(1 + 16 * w + m) * GS + d] = (f16)acc[p][q];
                }
            }
            if (t < 65) Gs[t] = (f16)la;                    // row xl=-1
            if (t >= 256 && t < 321) Gs[129 * GS + (t - 256)] = (f16)ra;  // row xl=128
        } else {
            // OOB row: zero the slot
#pragma unroll
            for (int k = 0; k < 17; ++k) {
                const int idx = t + 512 * k;
                if (idx < GROW * GS) Gs[idx] = (f16)0.f;
            }
        }
        __syncthreads();                  // slot r%3 published

        // ---- emit out row ye = y0 + r - 2 ----
        if (r >= 2) {
            const int ye = y0 + r - 2;
            const f16* g0 = GR + ((r - 2) % 3) * (GROW * GS);
            const f16* g1 = GR + ((r - 1) % 3) * (GROW * GS);
            const f16* g2 = GR + (r % 3) * (GROW * GS);
#pragma unroll
            for (int k = 0; k < 9; ++k) {
                const int d = 8 * k + w;
                if (d < ND) {
                    float v[4];
#pragma unroll
                    for (int vv = 0; vv < 4; ++vv) {
                        const int xi = (2 * l + vv) * GS + d;
                        v[vv] = (float)g0[xi] + (float)g1[xi] + (float)g2[xi];
                    }
                    f32x2 o;
                    o[0] = (v[0] + v[1] + v[2]) * INV;
                    o[1] = (v[1] + v[2] + v[3]) * INV;
                    f32x2* dst = (f32x2*)(outb + (size_t)d * WH + (size_t)ye * WF + X0 + 2 * l);
                    __builtin_nontemporal_store(o, dst);
                }
            }
        }
        __syncthreads();                  // box reads done before slot reuse
    }
}

// ---------------------------------------------------------------------------
extern "C" void kernel_launch(void* const* d_in, const int* in_sizes, int n_in,
                              void* d_out, int out_size, void* d_ws, size_t ws_size,
                              hipStream_t stream) {
    const float* x0 = (const float*)d_in[0];
    const float* x1 = (const float*)d_in[1];
    float* out = (float*)d_out;
    (void)d_ws; (void)ws_size; (void)in_sizes; (void)n_in; (void)out_size;

    corr_fused<<<dim3(512), dim3(512), 0, stream>>>(x0, x1, out);
}

// Round 20
// 152.941 us; speedup vs baseline: 1.1910x; 1.1910x over previous
//
#include <hip/hip_runtime.h>

#define WF 512
#define HF 256
#define CF 64
#define NDTOT 65
#define DP 72            // padded d-stride in ws (f16), 144 B rows
#define AP 36            // f16 ch-stride of SA/SB (72 B rows, b64-aligned)

static constexpr size_t CH  = (size_t)HF * WF;
static constexpr size_t WH  = (size_t)HF * WF;
static constexpr float  INV = 1.0f / 576.0f;

typedef _Float16 f16;
typedef _Float16 f16x4 __attribute__((ext_vector_type(4)));
typedef _Float16 f16x8 __attribute__((ext_vector_type(8)));
typedef float    f32x4 __attribute__((ext_vector_type(4)));
typedef unsigned int u32x4 __attribute__((ext_vector_type(4)));

// ---------------------------------------------------------------------------
// k1 (R20): banded Gram via MFMA, single-f16 (validated R16+), FULL-WIDTH:
// block = (b, y), 512 thr = 8 waves, covers all 512 cols.
//  - inputs read EXACTLY ONCE chip-wide (zero halo duplication): per 32-ch
//    half, x0[32][512] + x1[32][512] staged via pure f32x4 runs — each
//    channel-row is one contiguous 2 KB burst;
//  - NO guards/clamps: OOB displacement cols handled by 32 zeroed border
//    rows on each side of SB (zeroed once, staging never touches them);
//  - frags read as f16x4 pairs (AP=36, 8B-aligned);
//  - wave w owns cols 64w..64w+63: 4 x-tiles x 5 band offsets = 20 accs,
//    8 shared B-frags (row = 64w+16(xt+p)+n, s=xt+p in [0,8));
//  - epilogue: validated band scatter -> [512][72] LDS tile -> coalesced
//    nontemporal uint4 stores (full ws row, contiguous).
// Band mapping d = 16p+n-m, C/D+frag layouts: validated R5-R19.
// ---------------------------------------------------------------------------
__global__ __launch_bounds__(512)
void corr_gram(const float* __restrict__ x0, const float* __restrict__ x1,
               f16* __restrict__ ws) {
    // XCD swizzle: consecutive y-rows of one b adjacent per XCD.
    const int f = blockIdx.x;              // [0, 1024)
    const int unit = (f & 7) * 128 + (f >> 3);
    const int b = unit >> 8;
    const int y = unit & 255;

    const int t = threadIdx.x;             // [0, 512)
    const int l = t & 63;
    const int w = t >> 6;                  // wave = 64-col group [0,8)
    const int n = l & 15;
    const int kq = l >> 4;

    __shared__ f16 S[39168];               // SA [512][36] @0, SB [576][36] @18432
    f16* SA = S;
    f16* SB = S + 18432;

    const float* x0r = x0 + (size_t)b * CF * CH + (size_t)y * WF;
    const float* x1r = x1 + (size_t)b * CF * CH + (size_t)y * WF;

    // zero SB border rows (0..31 and 544..575) ONCE; staging never writes them
    if (t < 64) {
        const int rb = (t < 32) ? t : (512 + t);
#pragma unroll
        for (int c = 0; c < AP; ++c) SB[rb * AP + c] = (f16)0.f;
    }

    // staging map: thread t owns col-group cg (4 cols) x channels c0+4k
    const int cg = t & 127;                // col-group: cols 4cg..4cg+3
    const int c0 = t >> 7;                 // [0,4)

    f32x4 acc[20];
#pragma unroll
    for (int i = 0; i < 20; ++i) acc[i] = (f32x4)0.0f;

#pragma unroll
    for (int h = 0; h < 2; ++h) {
        // ---- load 16 f32x4 (A 8, B 8): contiguous 2 KB bursts per ch-row ----
        f32x4 av[8], bv[8];
#pragma unroll
        for (int k = 0; k < 8; ++k) {
            const size_t cofs = (size_t)(32 * h + c0 + 4 * k) * CH + 4 * cg;
            av[k] = *(const f32x4*)(x0r + cofs);
            bv[k] = *(const f32x4*)(x1r + cofs);
        }
        // ---- convert + col-major LDS write ----
#pragma unroll
        for (int k = 0; k < 8; ++k) {
            const int c = c0 + 4 * k;
#pragma unroll
            for (int j = 0; j < 4; ++j) {
                SA[(4 * cg + j) * AP + c] = (f16)av[k][j];
                SB[(32 + 4 * cg + j) * AP + c] = (f16)bv[k][j];
            }
        }
        __syncthreads();                   // half h staged

        // ---- MFMA: 4 A-frags, 8 B-frags, 20 MFMAs ----
        f16x8 a[4];
#pragma unroll
        for (int xt = 0; xt < 4; ++xt) {
            const int col = 64 * w + 16 * xt + n;
            const f16x4 lo = *(const f16x4*)&SA[col * AP + kq * 8];
            const f16x4 hi = *(const f16x4*)&SA[col * AP + kq * 8 + 4];
            a[xt][0] = lo[0]; a[xt][1] = lo[1]; a[xt][2] = lo[2]; a[xt][3] = lo[3];
            a[xt][4] = hi[0]; a[xt][5] = hi[1]; a[xt][6] = hi[2]; a[xt][7] = hi[3];
        }
#pragma unroll
        for (int s = 0; s < 8; ++s) {
            const int row = 64 * w + 16 * s + n;
            const f16x4 lo = *(const f16x4*)&SB[row * AP + kq * 8];
            const f16x4 hi = *(const f16x4*)&SB[row * AP + kq * 8 + 4];
            f16x8 bf;
            bf[0] = lo[0]; bf[1] = lo[1]; bf[2] = lo[2]; bf[3] = lo[3];
            bf[4] = hi[0]; bf[5] = hi[1]; bf[6] = hi[2]; bf[7] = hi[3];
#pragma unroll
            for (int xt = 0; xt < 4; ++xt) {
                const int p = s - xt;
                if (p >= 0 && p < 5)
                    acc[xt * 5 + p] = __builtin_amdgcn_mfma_f32_16x16x32_f16(a[xt], bf, acc[xt * 5 + p], 0, 0, 0);
            }
        }
        __syncthreads();                   // reads done before restage/epilogue
    }

    // ---- epilogue: band scatter -> [512][72] tile -> nt coalesced stores ----
    f16* eb = S;
#pragma unroll
    for (int xt = 0; xt < 4; ++xt) {
#pragma unroll
        for (int p = 0; p < 5; ++p) {
#pragma unroll
            for (int q = 0; q < 4; ++q) {
                const int m = kq * 4 + q;
                const int xl = 64 * w + 16 * xt + m;
                const int d = 16 * p + n - m;
                if ((unsigned)d < (unsigned)NDTOT)
                    eb[xl * DP + d] = (f16)acc[xt * 5 + p][q];
            }
        }
    }
    // zero pad d=65..71: thread t owns col t
#pragma unroll
    for (int dd = 0; dd < 7; ++dd) eb[t * DP + NDTOT + dd] = (f16)0.f;
    __syncthreads();

    // nt store: 512*72 f16 = 73728 B = 4608 x 16B chunks, 9 per thread
    u32x4* dst = (u32x4*)(ws + ((size_t)(b * HF + y) * WF) * DP);
    const u32x4* src = (const u32x4*)eb;
#pragma unroll
    for (int i = 0; i < 9; ++i)
        __builtin_nontemporal_store(src[t + 512 * i], &dst[t + 512 * i]);
}

// ---------------------------------------------------------------------------
// k2: 3x3 box-sum over ws + scale (R16's validated version).
// grid (16 x-tiles of 32, 32 y-tiles of 8, b); 256 thr.
// ---------------------------------------------------------------------------
__global__ __launch_bounds__(256)
void corr_box(const f16* __restrict__ ws, float* __restrict__ out) {
    const int xt = blockIdx.x;
    const int yt = blockIdx.y;
    const int b = blockIdx.z;
    const int t = threadIdx.x;
    const int x0b = xt * 32, y0 = yt * 8;

    __shared__ f16 S[10 * 34][DP];     // 48.96 KB

    for (int u = 0; u < 10; ++u) {
        const int yy = y0 - 1 + u;
        const bool yok = (unsigned)yy < (unsigned)HF;
        const f16* src = ws + ((size_t)(b * HF + yy) * WF + (x0b - 1)) * DP;
#pragma unroll
        for (int sub = 0; sub < 2; ++sub) {
            const int idx = sub * 256 + t;
            if (idx < 306) {
                const int v = idx / 9, dg = idx - v * 9;
                const int xx = x0b - 1 + v;
                f16x8 val;
#pragma unroll
                for (int jj = 0; jj < 8; ++jj) val[jj] = (f16)0.f;
                if (yok && (unsigned)xx < (unsigned)WF)
                    val = *(const f16x8*)(src + (size_t)v * DP + dg * 8);
                *(f16x8*)&S[u * 34 + v][dg * 8] = val;
            }
        }
    }
    __syncthreads();

    const int ly = t >> 5, lx = t & 31;
    const int yg = y0 + ly, xg = x0b + lx;
    float* o0 = out + (size_t)b * NDTOT * WH + (size_t)yg * WF + xg;

#pragma unroll 1
    for (int dg = 0; dg < 9; ++dg) {
        f16x8 s;
#pragma unroll
        for (int jj = 0; jj < 8; ++jj) s[jj] = (f16)0.f;
#pragma unroll
        for (int du = 0; du < 3; ++du)
#pragma unroll
            for (int dv = 0; dv < 3; ++dv)
                s += *(const f16x8*)&S[(ly + du) * 34 + (lx + dv)][dg * 8];
#pragma unroll
        for (int jj = 0; jj < 8; ++jj) {
            const int d = dg * 8 + jj;
            if (d < NDTOT) o0[(size_t)d * WH] = (float)s[jj] * INV;
        }
    }
}

// ---------------------------------------------------------------------------
// Emergency fallback (tiny ws): direct computation, slow but correct.
// ---------------------------------------------------------------------------
__global__ void corr_naive(const float* __restrict__ x0, const float* __restrict__ x1,
                           float* __restrict__ out) {
    const size_t total = (size_t)4 * NDTOT * WH;
    size_t idx = (size_t)blockIdx.x * blockDim.x + threadIdx.x;
    if (idx >= total) return;
    const int j = (int)(idx % WF);
    const int i = (int)((idx / WF) % HF);
    const int d = (int)((idx / WH) % NDTOT);
    const int b = (int)(idx / ((size_t)NDTOT * WH));
    const int disp = d - 32;
    float s = 0.f;
    for (int u = i - 1; u <= i + 1; ++u) {
        if (u < 0 || u >= HF) continue;
        for (int v = j - 1; v <= j + 1; ++v) {
            if (v < 0 || v >= WF) continue;
            const int v1c = v + disp;
            if (v1c < 0 || v1c >= WF) continue;
            const float* p0 = x0 + (size_t)b * CF * CH + (size_t)u * WF + v;
            const float* p1 = x1 + (size_t)b * CF * CH + (size_t)u * WF + v1c;
            for (int c = 0; c < CF; ++c)
                s += p0[(size_t)c * CH] * p1[(size_t)c * CH];
        }
    }
    out[idx] = s * INV;
}

// ---------------------------------------------------------------------------
extern "C" void kernel_launch(void* const* d_in, const int* in_sizes, int n_in,
                              void* d_out, int out_size, void* d_ws, size_t ws_size,
                              hipStream_t stream) {
    const float* x0 = (const float*)d_in[0];
    const float* x1 = (const float*)d_in[1];
    float* out = (float*)d_out;

    const size_t wsNeed = (size_t)4 * HF * WF * DP * sizeof(f16);  // 75.5 MB

    if (ws_size >= wsNeed) {
        f16* ws = (f16*)d_ws;
        corr_gram<<<dim3(1024), dim3(512), 0, stream>>>(x0, x1, ws);
        corr_box<<<dim3(16, 32, 4), dim3(256), 0, stream>>>(ws, out);
    } else {
        const size_t total = (size_t)4 * NDTOT * WH;
        const int blocks = (int)((total + 255) / 256);
        corr_naive<<<dim3(blocks), dim3(256), 0, stream>>>(x0, x1, out);
    }
}